// Round 1
// baseline (441.254 us; speedup 1.0000x reference)
//
#include <hip/hip_runtime.h>

// SpectralLayerNorm: complex (2-channel) layer norm with 2x2 whitening.
// x: (B,S,D,2) fp32, gamma: (D,3), beta: (D,2). One block per token (B*S tokens).
// Key folds:
//  - eigh-based inverse sqrt of 2x2 SPD matrix -> closed form
//  - reference's Gt[k'] = G[k' % d] with k' = dd*bs + k and bs % d == 0
//    => gamma matrix is G[token % d], foldable into the whitening matrix.

constexpr int D = 2048;
constexpr int THREADS = 256;          // 4 waves; each thread owns 8 complex pairs (4 float4)
constexpr float EPSV = 1e-5f;

__global__ __launch_bounds__(THREADS)
void spectral_ln_kernel(const float* __restrict__ x,
                        const float* __restrict__ gamma,
                        const float* __restrict__ beta,
                        float* __restrict__ out)
{
    const int k = blockIdx.x;            // token index
    const int t = threadIdx.x;
    const long base = (long)k * (D * 2);

    // ---- load 16 floats (8 complex pairs) per thread, coalesced float4 ----
    const float4* __restrict__ xin = (const float4*)(x + base);
    float4 v[4];
#pragma unroll
    for (int j = 0; j < 4; ++j) v[j] = xin[t * 4 + j];

    // ---- phase 1: complex mean over D ----
    float sr = 0.f, si = 0.f;
#pragma unroll
    for (int j = 0; j < 4; ++j) { sr += v[j].x + v[j].z; si += v[j].y + v[j].w; }
#pragma unroll
    for (int o = 32; o > 0; o >>= 1) {
        sr += __shfl_xor(sr, o, 64);
        si += __shfl_xor(si, o, 64);
    }
    __shared__ float red[4][3];
    const int wid = t >> 6, lane = t & 63;
    if (lane == 0) { red[wid][0] = sr; red[wid][1] = si; }
    __syncthreads();
    const float mu_r = (red[0][0] + red[1][0] + red[2][0] + red[3][0]) * (1.0f / D);
    const float mu_i = (red[0][1] + red[1][1] + red[2][1] + red[3][1]) * (1.0f / D);
    __syncthreads();   // LDS reused below

    // ---- center in registers + phase 2: 2x2 covariance of centered data ----
    float rr = 0.f, ri = 0.f, ii = 0.f;
#pragma unroll
    for (int j = 0; j < 4; ++j) {
        v[j].x -= mu_r; v[j].y -= mu_i; v[j].z -= mu_r; v[j].w -= mu_i;
        rr += v[j].x * v[j].x + v[j].z * v[j].z;
        ri += v[j].x * v[j].y + v[j].z * v[j].w;
        ii += v[j].y * v[j].y + v[j].w * v[j].w;
    }
#pragma unroll
    for (int o = 32; o > 0; o >>= 1) {
        rr += __shfl_xor(rr, o, 64);
        ri += __shfl_xor(ri, o, 64);
        ii += __shfl_xor(ii, o, 64);
    }
    if (lane == 0) { red[wid][0] = rr; red[wid][1] = ri; red[wid][2] = ii; }
    __syncthreads();
    const float inv_dm1 = 1.0f / (D - 1);
    const float a = (red[0][0] + red[1][0] + red[2][0] + red[3][0]) * inv_dm1 + EPSV;
    const float b = (red[0][1] + red[1][1] + red[2][1] + red[3][1]) * inv_dm1;
    const float c = (red[0][2] + red[1][2] + red[2][2] + red[3][2]) * inv_dm1 + EPSV;

    // ---- closed-form symmetric inverse sqrt of [[a,b],[b,c]] ----
    const float s   = sqrtf(a * c - b * b);
    const float tt  = sqrtf(a + c + 2.f * s);
    const float inv = 1.f / (s * tt);
    const float si00 = (c + s) * inv;
    const float si01 = -b * inv;
    const float si11 = (a + s) * inv;

    // ---- fold token-indexed gamma: M = [[g0,g1],[g1,g2]] @ std_inv ----
    const int m = k & (D - 1);           // k % 2048 (bs multiple of D => token-indexed)
    const float g0 = gamma[m * 3 + 0];
    const float g1 = gamma[m * 3 + 1];
    const float g2 = gamma[m * 3 + 2];
    const float M00 = g0 * si00 + g1 * si01;
    const float M01 = g0 * si01 + g1 * si11;
    const float M10 = g1 * si00 + g2 * si01;
    const float M11 = g1 * si01 + g2 * si11;

    // ---- apply M + beta, coalesced float4 stores ----
    const float4* __restrict__ bp = (const float4*)beta;
    float4* __restrict__ op = (float4*)(out + base);
#pragma unroll
    for (int j = 0; j < 4; ++j) {
        const float4 bt = bp[t * 4 + j];
        float4 o4;
        o4.x = M00 * v[j].x + M01 * v[j].y + bt.x;
        o4.y = M10 * v[j].x + M11 * v[j].y + bt.y;
        o4.z = M00 * v[j].z + M01 * v[j].w + bt.z;
        o4.w = M10 * v[j].z + M11 * v[j].w + bt.w;
        op[t * 4 + j] = o4;
    }
}

extern "C" void kernel_launch(void* const* d_in, const int* in_sizes, int n_in,
                              void* d_out, int out_size, void* d_ws, size_t ws_size,
                              hipStream_t stream) {
    const float* x     = (const float*)d_in[0];
    const float* gamma = (const float*)d_in[1];
    const float* beta  = (const float*)d_in[2];
    float* out = (float*)d_out;
    const int n_tokens = in_sizes[0] / (D * 2);   // B*S = 16384
    spectral_ln_kernel<<<dim3(n_tokens), dim3(THREADS), 0, stream>>>(x, gamma, beta, out);
}

// Round 2
// 435.383 us; speedup vs baseline: 1.0135x; 1.0135x over previous
//
#include <hip/hip_runtime.h>

// SpectralLayerNorm: complex (2-channel) layer norm with 2x2 whitening.
// x: (B,S,D,2) fp32, gamma: (D,3), beta: (D,2), out fp32.
// One WAVE per token (4 waves / 256-thread block), no LDS, no barriers.
// Analytical folds:
//  - eigh-based inverse sqrt of SPD 2x2 -> closed form:
//    s=sqrt(det), t=sqrt(trace+2s), A^{-1/2} = [[c+s,-b],[-b,a+s]]/(s*t)
//  - Gt[k'] = G[k' % d] with k' = dd*bs + tok and bs % d == 0
//    => per-token 2x2 gamma G[tok % d], folded into whitening: M = G @ A^{-1/2}
//  - one-pass raw moments: cov = (Sxy - Sx*mu_y)/(D-1)

constexpr int D = 2048;
constexpr float EPSV = 1e-5f;

__global__ __launch_bounds__(256)
void spectral_ln_kernel(const float4* __restrict__ x4,
                        const float* __restrict__ gamma,
                        const float4* __restrict__ beta4,
                        float4* __restrict__ out4,
                        int n_tokens)
{
    const int lane = threadIdx.x & 63;
    const int wid  = threadIdx.x >> 6;
    const int tok  = blockIdx.x * 4 + wid;
    if (tok >= n_tokens) return;
    const long base = (long)tok * (D * 2 / 4);     // 1024 float4 per token

    // ---- 16 wave-contiguous float4 loads (1 KB/instruction, fully coalesced)
    const float4* __restrict__ xin = x4 + base;
    float4 v[16];
#pragma unroll
    for (int j = 0; j < 16; ++j) v[j] = xin[j * 64 + lane];

    // ---- one-pass raw moments ----
    float sr = 0.f, si = 0.f, rr = 0.f, ri = 0.f, ii = 0.f;
#pragma unroll
    for (int j = 0; j < 16; ++j) {
        sr += v[j].x + v[j].z;  si += v[j].y + v[j].w;
        rr += v[j].x * v[j].x + v[j].z * v[j].z;
        ri += v[j].x * v[j].y + v[j].z * v[j].w;
        ii += v[j].y * v[j].y + v[j].w * v[j].w;
    }
    // single 6-step butterfly over the wave (all lanes end with full sums)
#pragma unroll
    for (int o = 32; o > 0; o >>= 1) {
        sr += __shfl_xor(sr, o, 64);
        si += __shfl_xor(si, o, 64);
        rr += __shfl_xor(rr, o, 64);
        ri += __shfl_xor(ri, o, 64);
        ii += __shfl_xor(ii, o, 64);
    }

    const float invD = 1.0f / D, inv_dm1 = 1.0f / (D - 1);
    const float mu_r = sr * invD, mu_i = si * invD;
    const float a = (rr - sr * mu_r) * inv_dm1 + EPSV;   // Srr - D*mu_r^2
    const float b = (ri - sr * mu_i) * inv_dm1;          // Sri - D*mu_r*mu_i
    const float c = (ii - si * mu_i) * inv_dm1 + EPSV;

    // ---- closed-form symmetric inverse sqrt of [[a,b],[b,c]] ----
    const float s   = sqrtf(a * c - b * b);
    const float t2  = sqrtf(a + c + 2.f * s);
    const float inv = 1.f / (s * t2);
    const float si00 = (c + s) * inv, si01 = -b * inv, si11 = (a + s) * inv;

    // ---- fold token-indexed gamma ----
    const int m = tok & (D - 1);
    const float g0 = gamma[m * 3 + 0], g1 = gamma[m * 3 + 1], g2 = gamma[m * 3 + 2];
    const float M00 = g0 * si00 + g1 * si01;
    const float M01 = g0 * si01 + g1 * si11;
    const float M10 = g1 * si00 + g2 * si01;
    const float M11 = g1 * si01 + g2 * si11;

    // ---- center, transform, add beta; wave-contiguous stores ----
    float4* __restrict__ op = out4 + base;
#pragma unroll
    for (int j = 0; j < 16; ++j) {
        const float4 bt = beta4[j * 64 + lane];   // 16 KB, L2-resident
        const float cr0 = v[j].x - mu_r, ci0 = v[j].y - mu_i;
        const float cr1 = v[j].z - mu_r, ci1 = v[j].w - mu_i;
        float4 o4;
        o4.x = M00 * cr0 + M01 * ci0 + bt.x;
        o4.y = M10 * cr0 + M11 * ci0 + bt.y;
        o4.z = M00 * cr1 + M01 * ci1 + bt.z;
        o4.w = M10 * cr1 + M11 * ci1 + bt.w;
        op[j * 64 + lane] = o4;
    }
}

extern "C" void kernel_launch(void* const* d_in, const int* in_sizes, int n_in,
                              void* d_out, int out_size, void* d_ws, size_t ws_size,
                              hipStream_t stream) {
    const float4* x4    = (const float4*)d_in[0];
    const float*  gamma = (const float*)d_in[1];
    const float4* beta4 = (const float4*)d_in[2];
    float4* out4 = (float4*)d_out;
    const int n_tokens = in_sizes[0] / (D * 2);    // B*S = 16384
    const int blocks = (n_tokens + 3) / 4;         // 4 tokens (waves) per block
    spectral_ln_kernel<<<dim3(blocks), dim3(256), 0, stream>>>(x4, gamma, beta4, out4, n_tokens);
}